// Round 11
// baseline (149.535 us; speedup 1.0000x reference)
//
#include <hip/hip_runtime.h>
#include <hip/hip_bf16.h>
#include <cstdint>
#include <cstddef>

// Problem constants
#define BS_TOT 12288   // 3 * 4096 rows
#define DIM    256     // embedding dim
#define BATCH_ 4096
#define NTILE  96      // BS_TOT / 128
#define NPAIR  4656    // NTILE*(NTILE+1)/2 — triangular tile pairs (incl diag)

typedef float f32x16 __attribute__((ext_vector_type(16)));
typedef int   i32x8  __attribute__((ext_vector_type(8)));

// ---------------------------------------------------------------------------
// Kernel 1: row-normalize -> fp8 e4m3 rows scaled by sqrt(10*log2(e)):
// acc = 10*log2(e)*cos, so epilogue exp(10 cos) = exp2(acc) = bare v_exp_f32.
// Also fp32 inv-norms (exact numerator path) + zero den + zero out.
// ---------------------------------------------------------------------------
__global__ __launch_bounds__(256) void normalize_kernel(const float* __restrict__ x,
                                                        uint8_t* __restrict__ xn,
                                                        float* __restrict__ invn,
                                                        float* __restrict__ den,
                                                        float* __restrict__ out,
                                                        int osz) {
  if (blockIdx.x == 0 && (int)threadIdx.x < osz) out[threadIdx.x] = 0.0f;
  const int wave = threadIdx.x >> 6;
  const int lane = threadIdx.x & 63;
  const int row  = blockIdx.x * 4 + wave;
  const float4 v = ((const float4*)(x + (size_t)row * DIM))[lane];
  float ss = v.x*v.x + v.y*v.y + v.z*v.z + v.w*v.w;
  #pragma unroll
  for (int off = 1; off < 64; off <<= 1) ss += __shfl_xor(ss, off, 64);
  const float s = 1.0f / fmaxf(sqrtf(ss), 1e-6f);
  if (lane == 0) { invn[row] = s; den[row] = 0.0f; }
  const float sc = s * 3.79828286f;   // sqrt(10 * log2(e))
  unsigned int w = __builtin_amdgcn_cvt_pk_fp8_f32(v.x * sc, v.y * sc, 0u, false);
  w = __builtin_amdgcn_cvt_pk_fp8_f32(v.z * sc, v.w * sc, w, true);
  ((unsigned int*)(xn + (size_t)row * DIM))[lane] = w;
}

// ---------------------------------------------------------------------------
// DPP add on the VALU pipe (not the DS pipe staging saturates — R6 lesson).
// ROW_SHR:N moves data to HIGHER lanes (lane i reads lane i-N): the AMD
// canonical inclusive-scan direction (rocPRIM wave reduce uses
// row_shr:1,2,4,8 + row_bcast:15/31). R10 used row_shl — suffix sums — bug.
// ---------------------------------------------------------------------------
template <int CTRL>
__device__ __forceinline__ float dpp_add(float v) {
  const int x = __builtin_amdgcn_update_dpp(0, __float_as_int(v), CTRL,
                                            0xF, 0xF, true);  // bound_ctrl: OOB=0
  return v + __int_as_float(x);
}
// Sum over each 32-lane group; result lands in lane 31 (half 0) / 63 (half 1).
__device__ __forceinline__ float dpp_sum32(float v) {
  v = dpp_add<0x111>(v);   // row_shr:1
  v = dpp_add<0x112>(v);   // row_shr:2
  v = dpp_add<0x114>(v);   // row_shr:4
  v = dpp_add<0x118>(v);   // row_shr:8  -> lanes 15/31/47/63 hold 16-row sums
  v = dpp_add<0x142>(v);   // row_bcast:15 -> lanes 31/63 hold 32-group sums
  return v;
}

// ---------------------------------------------------------------------------
// Kernel 2: SYMMETRIC triangular tile grid (tI <= tJ), MX-scaled fp8 MFMA
// 32x32x64, ONE tile computed per pair (upper triangle only — no mirror
// MFMA). Per block: stage panels A,B once (R7 layout), 16 MFMA/wave, then
// the epilogue produces BOTH den contributions from the same exp values:
//   col sums (over rows)  -> in-register            -> den[tJ cols]
//   row sums (over cols)  -> 5-op DPP chains (VALU) -> den[tI rows]
// Diagonal blocks: col sums only (tile symmetric, counted once).
//
// LDS: 32-B-unit XOR swizzle  addr = row*256 + ((k32 ^ (row&7))*32) + sub16
// Fragment ks: lane (l31,half) reads 32 B at unit (2ks+half)^(l31&7) —
// 32-B aligned, loaded as one i32x8 (2 x ds_read_b128).
// C/D layout (HW-verified): col = lane&31, row = (reg&3)+8*(reg>>2)+4*half.
// Mask: exclude iff col%4 == row%4  ->  ((l31 ^ r) & 3) == 0.
// ---------------------------------------------------------------------------
__global__ __launch_bounds__(256, 2) void gemm_den_kernel(const uint8_t* __restrict__ xn,
                                                          float* __restrict__ den) {
  __shared__ __align__(16) uint8_t As[128 * 256];   // 32 KB
  __shared__ __align__(16) uint8_t Bs[128 * 256];   // 32 KB

  const int tid = threadIdx.x;

  // triangular decode: blockIdx.x -> (tI <= tJ)
  const int t = blockIdx.x;
  int j = (int)((sqrtf(8.0f * (float)t + 1.0f) - 1.0f) * 0.5f);
  while ((j + 1) * (j + 2) / 2 <= t) j++;
  while (j * (j + 1) / 2 > t) j--;
  const int tI = t - j * (j + 1) / 2;   // 0..j
  const int tJ = j;
  const bool offd = (tI != tJ);

  const int wave = tid >> 6, lane = tid & 63;
  const int wr   = wave >> 1, wc = wave & 1;
  const int l31  = lane & 31, half = lane >> 5;

  const uint8_t* Ab = xn + (size_t)tI * 128 * DIM;
  const uint8_t* Bb = xn + (size_t)tJ * 128 * DIM;

  // ---- Stage A and B: 8 coalesced 16-B chunks each, swizzled b128 writes.
  int4 chA[8], chB[8];
  #pragma unroll
  for (int c = 0; c < 8; c++) {
    const int q = c * 256 + tid;
    const size_t off = (size_t)(q >> 4) * DIM + (size_t)(q & 15) * 16;
    chA[c] = *(const int4*)(Ab + off);
    chB[c] = *(const int4*)(Bb + off);
  }
  #pragma unroll
  for (int c = 0; c < 8; c++) {
    const int q   = c * 256 + tid;
    const int row = q >> 4, k16 = q & 15;
    const int wa  = row * 256 + (((k16 >> 1) ^ (row & 7)) * 32) + (k16 & 1) * 16;
    *(int4*)(As + wa) = chA[c];
    *(int4*)(Bs + wa) = chB[c];
  }
  __syncthreads();   // the ONLY barrier

  // ---- K-loop: 4 steps of K=64; 4 aligned i32x8 frag loads + 4 MFMA.
  const int e7 = l31 & 7;
  const int rowA0 = (wr * 64 + l31) * 256;
  const int rowB0 = (wc * 64 + l31) * 256;

  f32x16 acc[2][2] = {};
  #pragma unroll
  for (int ks = 0; ks < 4; ks++) {
    const int u = ((2 * ks + half) ^ e7) * 32;
    i32x8 af[2], bf[2];
    af[0] = *(const i32x8*)(As + rowA0 + u);
    af[1] = *(const i32x8*)(As + rowA0 + 32 * 256 + u);
    bf[0] = *(const i32x8*)(Bs + rowB0 + u);
    bf[1] = *(const i32x8*)(Bs + rowB0 + 32 * 256 + u);
    #pragma unroll
    for (int mi = 0; mi < 2; mi++)
      #pragma unroll
      for (int ni = 0; ni < 2; ni++)
        acc[mi][ni] = __builtin_amdgcn_mfma_scale_f32_32x32x64_f8f6f4(
            af[mi], bf[ni], acc[mi][ni], 0, 0, 0, 0x7F7F7F7F, 0, 0x7F7F7F7F);
  }

  // ---- Epilogue: E = exp2(acc) (temp+log2e pre-folded), masked.
  // Col sums in-register -> den[tJ]; row sums via DPP (VALU) -> den[tI].
  const int colBase = tJ * 128 + wc * 64;
  const int rowBase = tI * 128 + wr * 64;
  float colsum[2] = {0.f, 0.f};

  #pragma unroll
  for (int mi = 0; mi < 2; mi++) {
    #pragma unroll
    for (int r = 0; r < 16; r++) {
      const bool inc = ((l31 ^ r) & 3) != 0;   // col%4 != row%4
      float e0 = __builtin_amdgcn_exp2f(acc[mi][0][r]);
      float e1 = __builtin_amdgcn_exp2f(acc[mi][1][r]);
      e0 = inc ? e0 : 0.0f;
      e1 = inc ? e1 : 0.0f;
      colsum[0] += e0;
      colsum[1] += e1;
      if (offd) {
        const float rv = dpp_sum32(e0 + e1);   // sum over the 32 col-lanes
        if (l31 == 31)                          // lanes 31 (half0) & 63 (half1)
          atomicAdd(&den[rowBase + mi * 32 + (r & 3) + 8 * (r >> 2) + 4 * half], rv);
      }
    }
  }
  #pragma unroll
  for (int ni = 0; ni < 2; ni++) {
    float cs = colsum[ni] + __shfl_xor(colsum[ni], 32, 64);
    if (half == 0) atomicAdd(&den[colBase + ni * 32 + l31], cs);
  }
}

// ---------------------------------------------------------------------------
// Kernel 3: numerators (fp32, exact path) + final loss.
// ---------------------------------------------------------------------------
__global__ __launch_bounds__(256) void loss_kernel(const float* __restrict__ x,
                                                   const float* __restrict__ invn,
                                                   const float* __restrict__ den,
                                                   float* __restrict__ out) {
  __shared__ float part[4];
  const int wave = threadIdx.x >> 6, lane = threadIdx.x & 63;
  const int p = blockIdx.x * 4 + wave;
  const float4 a = ((const float4*)(x + (size_t)p * DIM))[lane];
  const float4 b = ((const float4*)(x + (size_t)(BATCH_ + p) * DIM))[lane];
  const float4 c = ((const float4*)(x + (size_t)(2*BATCH_ + p) * DIM))[lane];
  float d12 = a.x*b.x + a.y*b.y + a.z*b.z + a.w*b.w;
  float d13 = a.x*c.x + a.y*c.y + a.z*c.z + a.w*c.w;
  float d23 = b.x*c.x + b.y*c.y + b.z*c.z + b.w*c.w;
  #pragma unroll
  for (int off = 1; off < 64; off <<= 1) {
    d12 += __shfl_xor(d12, off, 64);
    d13 += __shfl_xor(d13, off, 64);
    d23 += __shfl_xor(d23, off, 64);
  }
  if (lane == 0) {
    const float s1 = invn[p], s2 = invn[BATCH_ + p], s3 = invn[2*BATCH_ + p];
    const float z12 = d12 * s1 * s2 * 10.0f;
    const float z13 = d13 * s1 * s3 * 10.0f;
    const float z23 = d23 * s2 * s3 * 10.0f;
    const float n12 = __expf(z12), n13 = __expf(z13), n23 = __expf(z23);
    const float e1 = den[p], e2 = den[BATCH_ + p], e3 = den[2*BATCH_ + p];
    part[wave] = __logf(n12 + e1) + __logf(n12 + e2) - 2.0f * z12
               + __logf(n13 + e1) + __logf(n13 + e3) - 2.0f * z13
               + __logf(n23 + e2) + __logf(n23 + e3) - 2.0f * z23;
  }
  __syncthreads();
  if (threadIdx.x == 0) {
    atomicAdd(out, (part[0] + part[1] + part[2] + part[3]) * (1.0f / (2.0f * BATCH_)));
  }
}

// ---------------------------------------------------------------------------
extern "C" void kernel_launch(void* const* d_in, const int* in_sizes, int n_in,
                              void* d_out, int out_size, void* d_ws, size_t ws_size,
                              hipStream_t stream) {
  const float* x = (const float*)d_in[0];
  float* out = (float*)d_out;

  char* ws = (char*)d_ws;
  uint8_t* xn   = (uint8_t*)ws;                                      // 3 MB fp8
  float*   invn = (float*)(ws + (size_t)BS_TOT * DIM);               // 48 KB
  float*   den  = (float*)(ws + (size_t)BS_TOT * DIM + BS_TOT * 4);  // 48 KB

  normalize_kernel<<<BS_TOT / 4, 256, 0, stream>>>(x, xn, invn, den, out, out_size);
  gemm_den_kernel<<<NPAIR, 256, 0, stream>>>(xn, den);
  loss_kernel<<<BATCH_ / 4, 256, 0, stream>>>(x, invn, den, out);
}

// Round 12
// 122.805 us; speedup vs baseline: 1.2177x; 1.2177x over previous
//
#include <hip/hip_runtime.h>
#include <hip/hip_bf16.h>
#include <cstdint>
#include <cstddef>

// Problem constants
#define BS_TOT 12288   // 3 * 4096 rows
#define DIM    256     // embedding dim
#define BATCH_ 4096
#define NTILE  96      // BS_TOT / 128
#define NPAIR  4656    // NTILE*(NTILE+1)/2 — triangular tile pairs (incl diag)

typedef float f32x16 __attribute__((ext_vector_type(16)));
typedef int   i32x8  __attribute__((ext_vector_type(8)));

// ---------------------------------------------------------------------------
// Kernel 1: row-normalize -> fp8 e4m3 rows scaled by sqrt(10*log2(e)):
// acc = 10*log2(e)*cos, so epilogue exp(10 cos) = exp2(acc) = bare v_exp_f32.
// Also fp32 inv-norms (exact numerator path) + zero den + zero out.
// ---------------------------------------------------------------------------
__global__ __launch_bounds__(256) void normalize_kernel(const float* __restrict__ x,
                                                        uint8_t* __restrict__ xn,
                                                        float* __restrict__ invn,
                                                        float* __restrict__ den,
                                                        float* __restrict__ out,
                                                        int osz) {
  if (blockIdx.x == 0 && (int)threadIdx.x < osz) out[threadIdx.x] = 0.0f;
  const int wave = threadIdx.x >> 6;
  const int lane = threadIdx.x & 63;
  const int row  = blockIdx.x * 4 + wave;
  const float4 v = ((const float4*)(x + (size_t)row * DIM))[lane];
  float ss = v.x*v.x + v.y*v.y + v.z*v.z + v.w*v.w;
  #pragma unroll
  for (int off = 1; off < 64; off <<= 1) ss += __shfl_xor(ss, off, 64);
  const float s = 1.0f / fmaxf(sqrtf(ss), 1e-6f);
  if (lane == 0) { invn[row] = s; den[row] = 0.0f; }
  const float sc = s * 3.79828286f;   // sqrt(10 * log2(e))
  unsigned int w = __builtin_amdgcn_cvt_pk_fp8_f32(v.x * sc, v.y * sc, 0u, false);
  w = __builtin_amdgcn_cvt_pk_fp8_f32(v.z * sc, v.w * sc, w, true);
  ((unsigned int*)(xn + (size_t)row * DIM))[lane] = w;
}

// ---------------------------------------------------------------------------
// Kernel 2: SYMMETRIC triangular tile grid (tI <= tJ), MX-scaled fp8 MFMA
// 32x32x64 (R8 structure — best measured: 56.8 us). Each block stages both
// panels once, computes BOTH tiles of the symmetric pair reusing the same
// LDS fragments (mirror MFMA costs idle MFMA slots, which measurement shows
// are cheaper than serial VALU/DPP row-sum chains — R11 lesson):
//   acc  = A·B^T -> masked col sums (in-register) -> den[tJ cols]
//   accT = B·A^T -> masked col sums (in-register) -> den[tI cols]
// Diagonal blocks: acc only.
//
// Micro-opts proven in R9-R11 (absmax 0.0 there): direct aligned i32x8 LDS
// loads (no marshal movs) and exp2 epilogue (temp+log2e folded into fp8).
//
// LDS: 32-B-unit XOR swizzle  addr = row*256 + ((k32 ^ (row&7))*32) + sub16
// Fragment ks: lane (l31,half) reads 32 B at unit (2ks+half)^(l31&7).
// C/D layout (HW-verified): col = lane&31, row = (reg&3)+8*(reg>>2)+4*half.
// Mask: exclude iff col%4 == row%4  ->  ((l31 ^ r) & 3) == 0.
// ---------------------------------------------------------------------------
__global__ __launch_bounds__(256, 2) void gemm_den_kernel(const uint8_t* __restrict__ xn,
                                                          float* __restrict__ den) {
  __shared__ __align__(16) uint8_t As[128 * 256];   // 32 KB
  __shared__ __align__(16) uint8_t Bs[128 * 256];   // 32 KB

  const int tid = threadIdx.x;

  // triangular decode: blockIdx.x -> (tI <= tJ)
  const int t = blockIdx.x;
  int j = (int)((sqrtf(8.0f * (float)t + 1.0f) - 1.0f) * 0.5f);
  while ((j + 1) * (j + 2) / 2 <= t) j++;
  while (j * (j + 1) / 2 > t) j--;
  const int tI = t - j * (j + 1) / 2;   // 0..j
  const int tJ = j;
  const bool offd = (tI != tJ);

  const int wave = tid >> 6, lane = tid & 63;
  const int wr   = wave >> 1, wc = wave & 1;
  const int l31  = lane & 31, half = lane >> 5;

  const uint8_t* Ab = xn + (size_t)tI * 128 * DIM;
  const uint8_t* Bb = xn + (size_t)tJ * 128 * DIM;

  // ---- Stage A and B: 8 coalesced 16-B chunks each, swizzled b128 writes.
  int4 chA[8], chB[8];
  #pragma unroll
  for (int c = 0; c < 8; c++) {
    const int q = c * 256 + tid;
    const size_t off = (size_t)(q >> 4) * DIM + (size_t)(q & 15) * 16;
    chA[c] = *(const int4*)(Ab + off);
    chB[c] = *(const int4*)(Bb + off);
  }
  #pragma unroll
  for (int c = 0; c < 8; c++) {
    const int q   = c * 256 + tid;
    const int row = q >> 4, k16 = q & 15;
    const int wa  = row * 256 + (((k16 >> 1) ^ (row & 7)) * 32) + (k16 & 1) * 16;
    *(int4*)(As + wa) = chA[c];
    *(int4*)(Bs + wa) = chB[c];
  }
  __syncthreads();   // the ONLY barrier

  // ---- K-loop: 4 steps of K=64; 4 aligned i32x8 frag loads + 4 fwd MFMA
  // (+ 4 mirror MFMA off-diagonal, same fragments swapped).
  const int e7 = l31 & 7;
  const int rowA0 = (wr * 64 + l31) * 256;
  const int rowB0 = (wc * 64 + l31) * 256;

  f32x16 acc[2][2]  = {};
  f32x16 accT[2][2] = {};
  #pragma unroll
  for (int ks = 0; ks < 4; ks++) {
    const int u = ((2 * ks + half) ^ e7) * 32;
    i32x8 af[2], bf[2];
    af[0] = *(const i32x8*)(As + rowA0 + u);
    af[1] = *(const i32x8*)(As + rowA0 + 32 * 256 + u);
    bf[0] = *(const i32x8*)(Bs + rowB0 + u);
    bf[1] = *(const i32x8*)(Bs + rowB0 + 32 * 256 + u);
    #pragma unroll
    for (int mi = 0; mi < 2; mi++)
      #pragma unroll
      for (int ni = 0; ni < 2; ni++)
        acc[mi][ni] = __builtin_amdgcn_mfma_scale_f32_32x32x64_f8f6f4(
            af[mi], bf[ni], acc[mi][ni], 0, 0, 0, 0x7F7F7F7F, 0, 0x7F7F7F7F);
    if (offd) {
      #pragma unroll
      for (int ni = 0; ni < 2; ni++)
        #pragma unroll
        for (int mi = 0; mi < 2; mi++)
          accT[ni][mi] = __builtin_amdgcn_mfma_scale_f32_32x32x64_f8f6f4(
              bf[ni], af[mi], accT[ni][mi], 0, 0, 0, 0x7F7F7F7F, 0, 0x7F7F7F7F);
    }
  }

  // ---- Epilogue: E = exp2(acc) (temp+log2e pre-folded); masked col sums.
  const int colBaseF = tJ * 128 + wc * 64;
  #pragma unroll
  for (int ni = 0; ni < 2; ni++) {
    float cs = 0.0f;
    #pragma unroll
    for (int mi = 0; mi < 2; mi++)
      #pragma unroll
      for (int r = 0; r < 16; r++)
        if (((l31 ^ r) & 3) != 0)          // include iff col%4 != row%4
          cs += __builtin_amdgcn_exp2f(acc[mi][ni][r]);
    cs += __shfl_xor(cs, 32, 64);
    if (half == 0) atomicAdd(&den[colBaseF + ni * 32 + l31], cs);
  }
  if (offd) {                              // mirror tile: cols belong to tI
    const int colBaseT = tI * 128 + wr * 64;
    #pragma unroll
    for (int mi = 0; mi < 2; mi++) {
      float cs = 0.0f;
      #pragma unroll
      for (int ni = 0; ni < 2; ni++)
        #pragma unroll
        for (int r = 0; r < 16; r++)
          if (((l31 ^ r) & 3) != 0)
            cs += __builtin_amdgcn_exp2f(accT[ni][mi][r]);
      cs += __shfl_xor(cs, 32, 64);
      if (half == 0) atomicAdd(&den[colBaseT + mi * 32 + l31], cs);
    }
  }
}

// ---------------------------------------------------------------------------
// Kernel 3: numerators (fp32, exact path) + final loss.
// ---------------------------------------------------------------------------
__global__ __launch_bounds__(256) void loss_kernel(const float* __restrict__ x,
                                                   const float* __restrict__ invn,
                                                   const float* __restrict__ den,
                                                   float* __restrict__ out) {
  __shared__ float part[4];
  const int wave = threadIdx.x >> 6, lane = threadIdx.x & 63;
  const int p = blockIdx.x * 4 + wave;
  const float4 a = ((const float4*)(x + (size_t)p * DIM))[lane];
  const float4 b = ((const float4*)(x + (size_t)(BATCH_ + p) * DIM))[lane];
  const float4 c = ((const float4*)(x + (size_t)(2*BATCH_ + p) * DIM))[lane];
  float d12 = a.x*b.x + a.y*b.y + a.z*b.z + a.w*b.w;
  float d13 = a.x*c.x + a.y*c.y + a.z*c.z + a.w*c.w;
  float d23 = b.x*c.x + b.y*c.y + b.z*c.z + b.w*c.w;
  #pragma unroll
  for (int off = 1; off < 64; off <<= 1) {
    d12 += __shfl_xor(d12, off, 64);
    d13 += __shfl_xor(d13, off, 64);
    d23 += __shfl_xor(d23, off, 64);
  }
  if (lane == 0) {
    const float s1 = invn[p], s2 = invn[BATCH_ + p], s3 = invn[2*BATCH_ + p];
    const float z12 = d12 * s1 * s2 * 10.0f;
    const float z13 = d13 * s1 * s3 * 10.0f;
    const float z23 = d23 * s2 * s3 * 10.0f;
    const float n12 = __expf(z12), n13 = __expf(z13), n23 = __expf(z23);
    const float e1 = den[p], e2 = den[BATCH_ + p], e3 = den[2*BATCH_ + p];
    part[wave] = __logf(n12 + e1) + __logf(n12 + e2) - 2.0f * z12
               + __logf(n13 + e1) + __logf(n13 + e3) - 2.0f * z13
               + __logf(n23 + e2) + __logf(n23 + e3) - 2.0f * z23;
  }
  __syncthreads();
  if (threadIdx.x == 0) {
    atomicAdd(out, (part[0] + part[1] + part[2] + part[3]) * (1.0f / (2.0f * BATCH_)));
  }
}

// ---------------------------------------------------------------------------
extern "C" void kernel_launch(void* const* d_in, const int* in_sizes, int n_in,
                              void* d_out, int out_size, void* d_ws, size_t ws_size,
                              hipStream_t stream) {
  const float* x = (const float*)d_in[0];
  float* out = (float*)d_out;

  char* ws = (char*)d_ws;
  uint8_t* xn   = (uint8_t*)ws;                                      // 3 MB fp8
  float*   invn = (float*)(ws + (size_t)BS_TOT * DIM);               // 48 KB
  float*   den  = (float*)(ws + (size_t)BS_TOT * DIM + BS_TOT * 4);  // 48 KB

  normalize_kernel<<<BS_TOT / 4, 256, 0, stream>>>(x, xn, invn, den, out, out_size);
  gemm_den_kernel<<<NPAIR, 256, 0, stream>>>(xn, den);
  loss_kernel<<<BATCH_ / 4, 256, 0, stream>>>(x, invn, den, out);
}